// Round 2
// baseline (360.060 us; speedup 1.0000x reference)
//
#include <hip/hip_runtime.h>

#define N_RAYS    131072
#define N_SAMPLES 128
#define FAR_DELTA 1e10f

#define WAVES_PER_BLOCK 4
#define RAYS_PER_WAVE   4
#define RAYS_PER_BLOCK  (WAVES_PER_BLOCK * RAYS_PER_WAVE)   // 16
#define FEAT_FLOATS     (N_SAMPLES * 3)                      // 384 floats per ray
#define LDS_FLOATS      (RAYS_PER_BLOCK * FEAT_FLOATS)       // 6144 floats = 24 KB

// 4 waves/block, 4 rays/wave. Features staged via LDS with coalesced float4
// loads; density/depth loaded as coalesced float2 per ray. Four independent
// scan chains per wave interleave to hide memory + shuffle latency.
__global__ __launch_bounds__(256) void VolumeRenderer_57612691308835_kernel(
    const float* __restrict__ density,      // [N, S]
    const float* __restrict__ feature,      // [N, S, 3]
    const float* __restrict__ depth,        // [N, S]
    float* __restrict__ out_feat,           // [N, 3]
    float* __restrict__ out_depth)          // [N]
{
    __shared__ float lds_feat[LDS_FLOATS];

    const int tid  = threadIdx.x;
    const int wave = tid >> 6;
    const int lane = tid & 63;
    const int blockRay0 = blockIdx.x * RAYS_PER_BLOCK;
    const int s0 = lane << 1;

    // ---- issue per-ray density/depth loads first (fully coalesced float2) ----
    float2 den[RAYS_PER_WAVE], dep[RAYS_PER_WAVE];
    #pragma unroll
    for (int r = 0; r < RAYS_PER_WAVE; ++r) {
        const long base = (long)(blockRay0 + wave * RAYS_PER_WAVE + r) * N_SAMPLES;
        den[r] = *(const float2*)(density + base + s0);
        dep[r] = *(const float2*)(depth   + base + s0);
    }

    // ---- stage 16 rays of features via coalesced float4 (16 B/lane) ----
    {
        const float4* gsrc = (const float4*)(feature + (long)blockRay0 * FEAT_FLOATS);
        float4* lds4 = (float4*)lds_feat;
        #pragma unroll
        for (int i = 0; i < LDS_FLOATS / 4 / 256; ++i)       // 6 iterations
            lds4[tid + i * 256] = gsrc[tid + i * 256];
    }
    __syncthreads();

    // ---- 4 independent rays per wave ----
    float fx[RAYS_PER_WAVE], fy[RAYS_PER_WAVE], fz[RAYS_PER_WAVE], dd[RAYS_PER_WAVE];

    #pragma unroll
    for (int r = 0; r < RAYS_PER_WAVE; ++r) {
        const int rl = wave * RAYS_PER_WAVE + r;             // ray index within block

        // feature for this lane's 2 samples from LDS (6 floats, 8B-aligned)
        const float* fp = lds_feat + rl * FEAT_FLOATS + s0 * 3;
        const float f0 = fp[0], f1 = fp[1], f2 = fp[2];      // sample s0: x,y,z
        const float f3 = fp[3], f4 = fp[4], f5 = fp[5];      // sample s0+1

        // deltas (last sample -> FAR_DELTA sentinel)
        const float d_next = __shfl_down(dep[r].x, 1);
        const float delta0 = dep[r].y - dep[r].x;
        const float delta1 = (lane == 63) ? FAR_DELTA : (d_next - dep[r].y);

        const float att0 = __expf(-den[r].x * delta0);
        const float att1 = __expf(-den[r].y * delta1);

        // inclusive product-scan of per-lane pair products across the wave
        float scan = att0 * att1;
        #pragma unroll
        for (int off = 1; off < 64; off <<= 1) {
            const float v = __shfl_up(scan, off);
            scan *= (lane >= off) ? v : 1.0f;
        }
        float excl = __shfl_up(scan, 1);
        if (lane == 0) excl = 1.0f;

        const float T0 = excl * att0;
        const float T1 = T0   * att1;
        const float w0 = T0 * (1.0f - att0);
        const float w1 = T1 * (1.0f - att1);

        fx[r] = w0 * f0 + w1 * f3;
        fy[r] = w0 * f1 + w1 * f4;
        fz[r] = w0 * f2 + w1 * f5;
        dd[r] = w0 * dep[r].x + w1 * dep[r].y;
    }

    // ---- butterfly reductions (4 rays x 4 values); chains are independent ----
    #pragma unroll
    for (int off = 32; off >= 1; off >>= 1) {
        #pragma unroll
        for (int r = 0; r < RAYS_PER_WAVE; ++r) {
            fx[r] += __shfl_xor(fx[r], off);
            fy[r] += __shfl_xor(fy[r], off);
            fz[r] += __shfl_xor(fz[r], off);
            dd[r] += __shfl_xor(dd[r], off);
        }
    }

    if (lane == 0) {
        #pragma unroll
        for (int r = 0; r < RAYS_PER_WAVE; ++r) {
            const int ray = blockRay0 + wave * RAYS_PER_WAVE + r;
            out_feat[ray * 3 + 0] = fx[r];
            out_feat[ray * 3 + 1] = fy[r];
            out_feat[ray * 3 + 2] = fz[r];
            out_depth[ray]        = dd[r];
        }
    }
}

extern "C" void kernel_launch(void* const* d_in, const int* in_sizes, int n_in,
                              void* d_out, int out_size, void* d_ws, size_t ws_size,
                              hipStream_t stream) {
    const float* density = (const float*)d_in[0];   // [N, S]
    const float* feature = (const float*)d_in[1];   // [N, S, 3]
    const float* depth   = (const float*)d_in[2];   // [N, S]

    float* out_feat  = (float*)d_out;                       // [N, 3]
    float* out_depth = (float*)d_out + (long)N_RAYS * 3;    // [N]

    const int grid = N_RAYS / RAYS_PER_BLOCK;               // 8192 blocks
    VolumeRenderer_57612691308835_kernel<<<grid, 256, 0, stream>>>(
        density, feature, depth, out_feat, out_depth);
}